// Round 4
// baseline (874.576 us; speedup 1.0000x reference)
//
#include <hip/hip_runtime.h>
#include <cstdint>
#include <cstddef>

// ---- problem constants ----
static constexpr int S_LEN = 2048;
static constexpr int HID   = 2048;
static constexpr int NH    = 32;
static constexpr int HD    = 128;
static constexpr int OD    = 4096;    // NH*HD
static constexpr int QKV_O = 12288;   // 3*OD

typedef __attribute__((ext_vector_type(8))) short bf16x8;
typedef __attribute__((ext_vector_type(4))) float f32x4;

__device__ __forceinline__ short f2bf(float f) {
  unsigned u = __float_as_uint(f);
  unsigned r = (u + 0x7fffu + ((u >> 16) & 1u)) >> 16;   // RNE
  return (short)r;
}
__device__ __forceinline__ float bf2f(short s) {
  return __uint_as_float(((unsigned)(unsigned short)s) << 16);
}

// ---------------- NT GEMM: C[M,N] = A[M,K] * B[N,K]^T ----------------
// AMODE/BMODE: 1 = fp32 source (convert during staging), 0 = bf16 source.
// CMODE: 0 = bf16 C, 1 = fp32 C.
#define BM 128
#define BN 128
#define BK 32

template <int AMODE, int BMODE, int CMODE>
__global__ __launch_bounds__(256, 2) void gemm_nt(
    const void* __restrict__ Ap, const void* __restrict__ Bp, void* __restrict__ Cp,
    int M, int N, int K) {
  __shared__ short Alds[BM * BK];
  __shared__ short Blds[BN * BK];
  const int tid  = threadIdx.x;
  const int lane = tid & 63;
  const int quad = lane >> 4;
  const int col  = lane & 15;
  const int wave = tid >> 6;
  const int m0 = blockIdx.y * BM;
  const int n0 = blockIdx.x * BN;
  const int wm = (wave & 1) * 64;
  const int wn = (wave >> 1) * 64;

  f32x4 acc[4][4] = {};

  for (int k0 = 0; k0 < K; k0 += BK) {
    __syncthreads();
#pragma unroll
    for (int it = 0; it < 2; ++it) {
      int idx = it * 256 + tid;          // 16B (8-elem) chunk index
      int row = idx >> 2;
      int ce  = (idx & 3) * 8;           // element offset within row
      // --- A ---
      bf16x8 av;
      if (AMODE == 1) {
        const float* ga = (const float*)Ap + (size_t)(m0 + row) * K + k0 + ce;
        float4 f0 = *(const float4*)ga;
        float4 f1 = *(const float4*)(ga + 4);
        av[0] = f2bf(f0.x); av[1] = f2bf(f0.y); av[2] = f2bf(f0.z); av[3] = f2bf(f0.w);
        av[4] = f2bf(f1.x); av[5] = f2bf(f1.y); av[6] = f2bf(f1.z); av[7] = f2bf(f1.w);
      } else {
        av = *(const bf16x8*)((const short*)Ap + (size_t)(m0 + row) * K + k0 + ce);
      }
      *(bf16x8*)&Alds[idx * 8] = av;
      // --- B ---
      bf16x8 bv;
      if (BMODE == 1) {
        const float* gb = (const float*)Bp + (size_t)(n0 + row) * K + k0 + ce;
        float4 f0 = *(const float4*)gb;
        float4 f1 = *(const float4*)(gb + 4);
        bv[0] = f2bf(f0.x); bv[1] = f2bf(f0.y); bv[2] = f2bf(f0.z); bv[3] = f2bf(f0.w);
        bv[4] = f2bf(f1.x); bv[5] = f2bf(f1.y); bv[6] = f2bf(f1.z); bv[7] = f2bf(f1.w);
      } else {
        bv = *(const bf16x8*)((const short*)Bp + (size_t)(n0 + row) * K + k0 + ce);
      }
      *(bf16x8*)&Blds[idx * 8] = bv;
    }
    __syncthreads();

    bf16x8 a[4], b[4];
#pragma unroll
    for (int i = 0; i < 4; ++i) {
      a[i] = *(const bf16x8*)&Alds[(wm + i * 16 + col) * BK + quad * 8];
      b[i] = *(const bf16x8*)&Blds[(wn + i * 16 + col) * BK + quad * 8];
    }
#pragma unroll
    for (int i = 0; i < 4; ++i)
#pragma unroll
      for (int j = 0; j < 4; ++j)
        acc[i][j] = __builtin_amdgcn_mfma_f32_16x16x32_bf16(a[i], b[j], acc[i][j], 0, 0, 0);
  }

  // epilogue: C/D layout col=lane&15, row=quad*4+reg (verified m89/m91)
#pragma unroll
  for (int i = 0; i < 4; ++i)
#pragma unroll
    for (int j = 0; j < 4; ++j)
#pragma unroll
      for (int r = 0; r < 4; ++r) {
        int rr = m0 + wm + i * 16 + quad * 4 + r;
        int cc = n0 + wn + j * 16 + col;
        if (CMODE == 1)
          ((float*)Cp)[(size_t)rr * N + cc] = acc[i][j][r];
        else
          ((short*)Cp)[(size_t)rr * N + cc] = f2bf(acc[i][j][r]);
      }
}

// ---------------- per-(s, q/k, head) RMSNorm + RoPE, in place on bf16 qkv ----------------
__global__ void norm_rope_kernel(short* __restrict__ qkv,
                                 const int* __restrict__ positions,
                                 const float* __restrict__ qw,
                                 const float* __restrict__ kw) {
  int item = blockIdx.x * 4 + (threadIdx.x >> 6);  // (s, which, head)
  int lane = threadIdx.x & 63;
  int head  = item & 31;
  int which = (item >> 5) & 1;
  int s     = item >> 6;
  const float* w = which ? kw : qw;
  short* base = qkv + (size_t)s * QKV_O + which * OD + head * HD;

  float x1 = bf2f(base[lane]);
  float x2 = bf2f(base[lane + 64]);
  float ss = x1 * x1 + x2 * x2;
#pragma unroll
  for (int d = 32; d; d >>= 1) ss += __shfl_xor(ss, d);
  float r = rsqrtf(ss * (1.0f / 128.0f) + 1e-5f);
  float xn1 = x1 * r * w[lane];
  float xn2 = x2 * r * w[lane + 64];

  float pos = (float)positions[s];
  // inv_freq = 10000^(-lane/64) = 2^(-lane*log2(10000)/64)
  float inv_freq = exp2f((float)lane * (-13.287712379549449f / 64.0f));
  float f = pos * inv_freq;
  float c = cosf(f), sn = sinf(f);
  base[lane]      = f2bf(xn1 * c - xn2 * sn);
  base[lane + 64] = f2bf(xn2 * c + xn1 * sn);
}

// ---------------- flash attention (causal), bf16 MFMA ----------------
#define L2E 1.4426950408889634f
__global__ __launch_bounds__(256, 2) void attn_kernel(
    const short* __restrict__ qkv, short* __restrict__ obuf) {
  __shared__ short Klds[32][136];      // K tile [kr][d], +8 pad
  __shared__ short Vt[128][40];        // V tile transposed [d][kr]
  __shared__ short Plds[4][32][40];    // per-wave P round-trip

  const int tid  = threadIdx.x;
  const int lane = tid & 63;
  const int wave = tid >> 6;
  const int quad = lane >> 4;
  const int col  = lane & 15;
  const int qt = blockIdx.x;
  const int h  = blockIdx.y;
  const int qbase = qt * 128 + wave * 32;

  // Q fragments (A-layout: m=lane&15, k=quad*8+j), 2 row-frags x 4 k-frags
  bf16x8 qf[2][4];
#pragma unroll
  for (int mi = 0; mi < 2; ++mi)
#pragma unroll
    for (int kf = 0; kf < 4; ++kf) {
      const short* p = qkv + (size_t)(qbase + mi * 16 + col) * QKV_O + h * HD + kf * 32 + quad * 8;
      qf[mi][kf] = *(const bf16x8*)p;
    }

  f32x4 o[2][8] = {};
  float m_i[2][4], l_i[2][4];
#pragma unroll
  for (int mi = 0; mi < 2; ++mi)
#pragma unroll
    for (int r = 0; r < 4; ++r) { m_i[mi][r] = -1e30f; l_i[mi][r] = 0.f; }

  const int ktiles = (qt + 1) * 4;
  for (int kt = 0; kt < ktiles; ++kt) {
    __syncthreads();   // previous iteration's LDS reads done
    {
      int r  = tid >> 3;
      int cb = (tid & 7) * 16;
      const short* kp = qkv + (size_t)(kt * 32 + r) * QKV_O + OD + h * HD + cb;
      const short* vp = qkv + (size_t)(kt * 32 + r) * QKV_O + 2 * OD + h * HD + cb;
      bf16x8 k0v = *(const bf16x8*)kp;
      bf16x8 k1v = *(const bf16x8*)(kp + 8);
      *(bf16x8*)&Klds[r][cb]     = k0v;
      *(bf16x8*)&Klds[r][cb + 8] = k1v;
      bf16x8 v0 = *(const bf16x8*)vp;
      bf16x8 v1 = *(const bf16x8*)(vp + 8);
#pragma unroll
      for (int i = 0; i < 8; ++i) Vt[cb + i][r] = v0[i];
#pragma unroll
      for (int i = 0; i < 8; ++i) Vt[cb + 8 + i][r] = v1[i];
    }
    __syncthreads();

    // S = Q K^T
    f32x4 sfr[2][2];
#pragma unroll
    for (int mi = 0; mi < 2; ++mi)
#pragma unroll
      for (int ni = 0; ni < 2; ++ni) {
        f32x4 acc = {};
#pragma unroll
        for (int kf = 0; kf < 4; ++kf) {
          bf16x8 b = *(const bf16x8*)&Klds[ni * 16 + col][kf * 32 + quad * 8];
          acc = __builtin_amdgcn_mfma_f32_16x16x32_bf16(qf[mi][kf], b, acc, 0, 0, 0);
        }
        sfr[mi][ni] = acc;
      }

    const float scale = 0.08838834764831845f;  // 128^-0.5
#pragma unroll
    for (int mi = 0; mi < 2; ++mi) {
      float mt[4];
#pragma unroll
      for (int r = 0; r < 4; ++r) {
        int qg  = qbase + mi * 16 + quad * 4 + r;
        float s0 = sfr[mi][0][r] * scale;
        float s1 = sfr[mi][1][r] * scale;
        if (kt * 32 + col > qg)      s0 = -1e30f;
        if (kt * 32 + 16 + col > qg) s1 = -1e30f;
        sfr[mi][0][r] = s0; sfr[mi][1][r] = s1;
        mt[r] = fmaxf(s0, s1);
      }
#pragma unroll
      for (int r = 0; r < 4; ++r) {
#pragma unroll
        for (int d = 8; d; d >>= 1) mt[r] = fmaxf(mt[r], __shfl_xor(mt[r], d));
        float mnew  = fmaxf(m_i[mi][r], mt[r]);
        float alpha = exp2f((m_i[mi][r] - mnew) * L2E);
        float p0 = exp2f((sfr[mi][0][r] - mnew) * L2E);
        float p1 = exp2f((sfr[mi][1][r] - mnew) * L2E);
        sfr[mi][0][r] = p0; sfr[mi][1][r] = p1;
        float rs = p0 + p1;
#pragma unroll
        for (int d = 8; d; d >>= 1) rs += __shfl_xor(rs, d);
        l_i[mi][r] = l_i[mi][r] * alpha + rs;
        m_i[mi][r] = mnew;
#pragma unroll
        for (int nf = 0; nf < 8; ++nf) o[mi][nf][r] *= alpha;
      }
      // P -> LDS (C-layout scatter), becomes A-layout contiguous rows
#pragma unroll
      for (int r = 0; r < 4; ++r) {
        Plds[wave][mi * 16 + quad * 4 + r][col]      = f2bf(sfr[mi][0][r]);
        Plds[wave][mi * 16 + quad * 4 + r][16 + col] = f2bf(sfr[mi][1][r]);
      }
    }
    __syncthreads();

    // O += P V
#pragma unroll
    for (int mi = 0; mi < 2; ++mi) {
      bf16x8 pa = *(const bf16x8*)&Plds[wave][mi * 16 + col][quad * 8];
#pragma unroll
      for (int nf = 0; nf < 8; ++nf) {
        bf16x8 vb = *(const bf16x8*)&Vt[nf * 16 + col][quad * 8];
        o[mi][nf] = __builtin_amdgcn_mfma_f32_16x16x32_bf16(pa, vb, o[mi][nf], 0, 0, 0);
      }
    }
  }

  // epilogue: O /= l, write bf16 [s][h*128+d]
#pragma unroll
  for (int mi = 0; mi < 2; ++mi)
#pragma unroll
    for (int r = 0; r < 4; ++r) {
      float inv = 1.0f / l_i[mi][r];
      int sg = qbase + mi * 16 + quad * 4 + r;
#pragma unroll
      for (int nf = 0; nf < 8; ++nf)
        obuf[(size_t)sg * OD + h * HD + nf * 16 + col] = f2bf(o[mi][nf][r] * inv);
    }
}

// ---------------- launcher ----------------
extern "C" void kernel_launch(void* const* d_in, const int* in_sizes, int n_in,
                              void* d_out, int out_size, void* d_ws, size_t ws_size,
                              hipStream_t stream) {
  (void)in_sizes; (void)n_in; (void)out_size; (void)ws_size;
  // Inputs fp32 (confirmed: bf16-read NaN probe, Round 2). Output fp32 (reference dtype).
  const float* hs   = (const float*)d_in[0];   // [2048][2048] f32
  const int*   pos  = (const int*)d_in[1];     // [2048] int32
  const float* qkvw = (const float*)d_in[2];   // [12288][2048] f32
  const float* qw   = (const float*)d_in[3];   // [128] f32
  const float* kw   = (const float*)d_in[4];   // [128] f32
  const float* ow   = (const float*)d_in[5];   // [2048][4096] f32
  float* out = (float*)d_out;                  // [2048][2048] f32

  // ws layout: [qkvb 48 MiB][obuf 16 MiB] = 64 MiB total
  char* ws = (char*)d_ws;
  short* qkvb = (short*)(ws);
  short* obuf = (short*)(ws + 50331648);

  // 1) qkv = hs @ qkv_w^T   (M=2048, N=12288, K=2048), convert-on-stage, bf16 C
  gemm_nt<1, 1, 0><<<dim3(QKV_O / BN, S_LEN / BM), 256, 0, stream>>>(hs, qkvw, qkvb, S_LEN, QKV_O, HID);

  // 2) RMSNorm + RoPE in place on q,k
  norm_rope_kernel<<<(S_LEN * 2 * NH) / 4, 256, 0, stream>>>(qkvb, pos, qw, kw);

  // 3) causal flash attention -> obuf [s][h*128+d] (bf16)
  attn_kernel<<<dim3(S_LEN / 128, NH), 256, 0, stream>>>(qkvb, obuf);

  // 4) out = obuf @ o_proj_w^T  (M=2048, N=2048, K=4096), A bf16 / B f32, fp32 C
  gemm_nt<0, 1, 1><<<dim3(HID / BN, S_LEN / BM), 256, 0, stream>>>(obuf, ow, out, S_LEN, HID, OD);
}

// Round 5
// 705.859 us; speedup vs baseline: 1.2390x; 1.2390x over previous
//
#include <hip/hip_runtime.h>
#include <cstdint>
#include <cstddef>

// ---- problem constants ----
static constexpr int S_LEN = 2048;
static constexpr int HID   = 2048;
static constexpr int NH    = 32;
static constexpr int HD    = 128;
static constexpr int OD    = 4096;    // NH*HD
static constexpr int QKV_O = 12288;   // 3*OD

#define AS1 __attribute__((address_space(1)))
#define AS3 __attribute__((address_space(3)))

typedef __attribute__((ext_vector_type(8))) short bf16x8;
typedef __attribute__((ext_vector_type(4))) float f32x4;
typedef __attribute__((ext_vector_type(4))) short s16x4;

__device__ __forceinline__ short f2bf(float f) {
  unsigned u = __float_as_uint(f);
  unsigned r = (u + 0x7fffu + ((u >> 16) & 1u)) >> 16;   // RNE
  return (short)r;
}
__device__ __forceinline__ float bf2f(short s) {
  return __uint_as_float(((unsigned)(unsigned short)s) << 16);
}

// ---------------- fp32 -> bf16 convert (bandwidth-bound) ----------------
__global__ void convert_kernel(const float* __restrict__ in, short* __restrict__ out, int n4) {
  int i = blockIdx.x * blockDim.x + threadIdx.x;
  if (i >= n4) return;
  float4 f = ((const float4*)in)[i];
  s16x4 s;
  s.x = f2bf(f.x); s.y = f2bf(f.y); s.z = f2bf(f.z); s.w = f2bf(f.w);
  ((s16x4*)out)[i] = s;
}

// ---------------- NT bf16 GEMM: C[M,N] = A[M,K] * B[N,K]^T ----------------
// m97 structure: 128x128 tile, BK=32, global_load_lds width16, 16x16x32 MFMA.
// CMODE: 0 = bf16 C, 1 = fp32 C.  ldc = C row stride (elements).
#define BM 128
#define BN 128
#define BK 32

template <int CMODE>
__global__ __launch_bounds__(256, 2) void gemm_nt_bf16(
    const short* __restrict__ A, const short* __restrict__ B, void* __restrict__ Cp,
    int K, int ldc) {
  __shared__ short Alds[BM * BK];   // unpadded: required by global_load_lds lane layout
  __shared__ short Blds[BN * BK];
  const int tid  = threadIdx.x;
  const int lane = tid & 63;
  const int quad = lane >> 4;
  const int col  = lane & 15;
  const int wave = tid >> 6;
  const int m0 = blockIdx.y * BM;
  const int n0 = blockIdx.x * BN;
  const int wm = (wave & 1) * 64;
  const int wn = (wave >> 1) * 64;

  f32x4 acc[4][4] = {};

  for (int k0 = 0; k0 < K; k0 += BK) {
    __syncthreads();
#pragma unroll
    for (int it = 0; it < 2; ++it) {
      int idx = it * 256 + tid;          // 16B chunk index
      int row = idx >> 2;
      int ce  = (idx & 3) * 8;           // element offset within row
      const short* ga = A + (size_t)(m0 + row) * K + k0 + ce;
      const short* gb = B + (size_t)(n0 + row) * K + k0 + ce;
      __builtin_amdgcn_global_load_lds((const AS1 unsigned*)ga, (AS3 unsigned*)&Alds[idx * 8], 16, 0, 0);
      __builtin_amdgcn_global_load_lds((const AS1 unsigned*)gb, (AS3 unsigned*)&Blds[idx * 8], 16, 0, 0);
    }
    __syncthreads();

    bf16x8 a[4], b[4];
#pragma unroll
    for (int i = 0; i < 4; ++i) {
      a[i] = *(const bf16x8*)&Alds[(wm + i * 16 + col) * BK + quad * 8];
      b[i] = *(const bf16x8*)&Blds[(wn + i * 16 + col) * BK + quad * 8];
    }
#pragma unroll
    for (int i = 0; i < 4; ++i)
#pragma unroll
      for (int j = 0; j < 4; ++j)
        acc[i][j] = __builtin_amdgcn_mfma_f32_16x16x32_bf16(a[i], b[j], acc[i][j], 0, 0, 0);
  }

  // epilogue: C/D layout col=lane&15, row=quad*4+reg (verified m89/m91)
#pragma unroll
  for (int i = 0; i < 4; ++i)
#pragma unroll
    for (int j = 0; j < 4; ++j)
#pragma unroll
      for (int r = 0; r < 4; ++r) {
        int rr = m0 + wm + i * 16 + quad * 4 + r;
        int cc = n0 + wn + j * 16 + col;
        if (CMODE == 1)
          ((float*)Cp)[(size_t)rr * ldc + cc] = acc[i][j][r];
        else
          ((short*)Cp)[(size_t)rr * ldc + cc] = f2bf(acc[i][j][r]);
      }
}

// ---------------- per-(s, q/k, head) RMSNorm + RoPE, in place on bf16 qkv ----------------
__global__ void norm_rope_kernel(short* __restrict__ qkv,
                                 const int* __restrict__ positions,
                                 const float* __restrict__ qw,
                                 const float* __restrict__ kw) {
  int item = blockIdx.x * 4 + (threadIdx.x >> 6);  // (s, which, head)
  int lane = threadIdx.x & 63;
  int head  = item & 31;
  int which = (item >> 5) & 1;
  int s     = item >> 6;
  const float* w = which ? kw : qw;
  short* base = qkv + (size_t)s * QKV_O + which * OD + head * HD;

  float x1 = bf2f(base[lane]);
  float x2 = bf2f(base[lane + 64]);
  float ss = x1 * x1 + x2 * x2;
#pragma unroll
  for (int d = 32; d; d >>= 1) ss += __shfl_xor(ss, d);
  float r = rsqrtf(ss * (1.0f / 128.0f) + 1e-5f);
  float xn1 = x1 * r * w[lane];
  float xn2 = x2 * r * w[lane + 64];

  float pos = (float)positions[s];
  float inv_freq = exp2f((float)lane * (-13.287712379549449f / 64.0f));
  float f = pos * inv_freq;
  float c = cosf(f), sn = sinf(f);
  base[lane]      = f2bf(xn1 * c - xn2 * sn);
  base[lane + 64] = f2bf(xn2 * c + xn1 * sn);
}

// ---------------- flash attention (causal), bf16 MFMA ----------------
#define L2E 1.4426950408889634f
__global__ __launch_bounds__(256, 2) void attn_kernel(
    const short* __restrict__ qkv, short* __restrict__ obuf) {
  __shared__ short Klds[32][136];      // K tile [kr][d], +8 pad
  __shared__ short Vt[128][40];        // V tile transposed [d][kr]
  __shared__ short Plds[4][32][40];    // per-wave P round-trip

  const int tid  = threadIdx.x;
  const int lane = tid & 63;
  const int wave = tid >> 6;
  const int quad = lane >> 4;
  const int col  = lane & 15;
  const int qt = blockIdx.x;
  const int h  = blockIdx.y;
  const int qbase = qt * 128 + wave * 32;

  bf16x8 qf[2][4];
#pragma unroll
  for (int mi = 0; mi < 2; ++mi)
#pragma unroll
    for (int kf = 0; kf < 4; ++kf) {
      const short* p = qkv + (size_t)(qbase + mi * 16 + col) * QKV_O + h * HD + kf * 32 + quad * 8;
      qf[mi][kf] = *(const bf16x8*)p;
    }

  f32x4 o[2][8] = {};
  float m_i[2][4], l_i[2][4];
#pragma unroll
  for (int mi = 0; mi < 2; ++mi)
#pragma unroll
    for (int r = 0; r < 4; ++r) { m_i[mi][r] = -1e30f; l_i[mi][r] = 0.f; }

  const int ktiles = (qt + 1) * 4;
  for (int kt = 0; kt < ktiles; ++kt) {
    __syncthreads();
    {
      int r  = tid >> 3;
      int cb = (tid & 7) * 16;
      const short* kp = qkv + (size_t)(kt * 32 + r) * QKV_O + OD + h * HD + cb;
      const short* vp = qkv + (size_t)(kt * 32 + r) * QKV_O + 2 * OD + h * HD + cb;
      bf16x8 k0v = *(const bf16x8*)kp;
      bf16x8 k1v = *(const bf16x8*)(kp + 8);
      *(bf16x8*)&Klds[r][cb]     = k0v;
      *(bf16x8*)&Klds[r][cb + 8] = k1v;
      bf16x8 v0 = *(const bf16x8*)vp;
      bf16x8 v1 = *(const bf16x8*)(vp + 8);
#pragma unroll
      for (int i = 0; i < 8; ++i) Vt[cb + i][r] = v0[i];
#pragma unroll
      for (int i = 0; i < 8; ++i) Vt[cb + 8 + i][r] = v1[i];
    }
    __syncthreads();

    f32x4 sfr[2][2];
#pragma unroll
    for (int mi = 0; mi < 2; ++mi)
#pragma unroll
      for (int ni = 0; ni < 2; ++ni) {
        f32x4 acc = {};
#pragma unroll
        for (int kf = 0; kf < 4; ++kf) {
          bf16x8 b = *(const bf16x8*)&Klds[ni * 16 + col][kf * 32 + quad * 8];
          acc = __builtin_amdgcn_mfma_f32_16x16x32_bf16(qf[mi][kf], b, acc, 0, 0, 0);
        }
        sfr[mi][ni] = acc;
      }

    const float scale = 0.08838834764831845f;
#pragma unroll
    for (int mi = 0; mi < 2; ++mi) {
      float mt[4];
#pragma unroll
      for (int r = 0; r < 4; ++r) {
        int qg  = qbase + mi * 16 + quad * 4 + r;
        float s0 = sfr[mi][0][r] * scale;
        float s1 = sfr[mi][1][r] * scale;
        if (kt * 32 + col > qg)      s0 = -1e30f;
        if (kt * 32 + 16 + col > qg) s1 = -1e30f;
        sfr[mi][0][r] = s0; sfr[mi][1][r] = s1;
        mt[r] = fmaxf(s0, s1);
      }
#pragma unroll
      for (int r = 0; r < 4; ++r) {
#pragma unroll
        for (int d = 8; d; d >>= 1) mt[r] = fmaxf(mt[r], __shfl_xor(mt[r], d));
        float mnew  = fmaxf(m_i[mi][r], mt[r]);
        float alpha = exp2f((m_i[mi][r] - mnew) * L2E);
        float p0 = exp2f((sfr[mi][0][r] - mnew) * L2E);
        float p1 = exp2f((sfr[mi][1][r] - mnew) * L2E);
        sfr[mi][0][r] = p0; sfr[mi][1][r] = p1;
        float rs = p0 + p1;
#pragma unroll
        for (int d = 8; d; d >>= 1) rs += __shfl_xor(rs, d);
        l_i[mi][r] = l_i[mi][r] * alpha + rs;
        m_i[mi][r] = mnew;
#pragma unroll
        for (int nf = 0; nf < 8; ++nf) o[mi][nf][r] *= alpha;
      }
#pragma unroll
      for (int r = 0; r < 4; ++r) {
        Plds[wave][mi * 16 + quad * 4 + r][col]      = f2bf(sfr[mi][0][r]);
        Plds[wave][mi * 16 + quad * 4 + r][16 + col] = f2bf(sfr[mi][1][r]);
      }
    }
    __syncthreads();

#pragma unroll
    for (int mi = 0; mi < 2; ++mi) {
      bf16x8 pa = *(const bf16x8*)&Plds[wave][mi * 16 + col][quad * 8];
#pragma unroll
      for (int nf = 0; nf < 8; ++nf) {
        bf16x8 vb = *(const bf16x8*)&Vt[nf * 16 + col][quad * 8];
        o[mi][nf] = __builtin_amdgcn_mfma_f32_16x16x32_bf16(pa, vb, o[mi][nf], 0, 0, 0);
      }
    }
  }

#pragma unroll
  for (int mi = 0; mi < 2; ++mi)
#pragma unroll
    for (int r = 0; r < 4; ++r) {
      float inv = 1.0f / l_i[mi][r];
      int sg = qbase + mi * 16 + quad * 4 + r;
#pragma unroll
      for (int nf = 0; nf < 8; ++nf)
        obuf[(size_t)sg * OD + h * HD + nf * 16 + col] = f2bf(o[mi][nf][r] * inv);
    }
}

// ---------------- launcher ----------------
extern "C" void kernel_launch(void* const* d_in, const int* in_sizes, int n_in,
                              void* d_out, int out_size, void* d_ws, size_t ws_size,
                              hipStream_t stream) {
  (void)in_sizes; (void)n_in; (void)out_size; (void)ws_size;
  const float* hs   = (const float*)d_in[0];   // [2048][2048] f32
  const int*   pos  = (const int*)d_in[1];     // [2048] int32
  const float* qkvw = (const float*)d_in[2];   // [12288][2048] f32
  const float* qw   = (const float*)d_in[3];   // [128] f32
  const float* kw   = (const float*)d_in[4];   // [128] f32
  const float* ow   = (const float*)d_in[5];   // [2048][4096] f32
  float* out = (float*)d_out;                  // [2048][2048] f32

  // Memory plan (64 MiB ws + d_out scratch):
  //   ws[ 0..48M): qkvb (bf16 qkv activations); later (post-attn) owb bf16 at ws[0..16M)
  //   ws[48..64M): wchunk (bf16 weight chunk) during GEMM1; obuf after attention
  //   d_out[0..8M): hsb (bf16 hidden) — dead before GEMM2 overwrites d_out
  char* ws = (char*)d_ws;
  short* qkvb   = (short*)(ws);
  short* wchunk = (short*)(ws + 50331648);
  short* obuf   = (short*)(ws + 50331648);
  short* owb    = (short*)(ws);
  short* hsb    = (short*)d_out;

  // 1) convert hidden_states -> bf16 (in d_out scratch)
  {
    int n4 = (S_LEN * HID) / 4;
    convert_kernel<<<(n4 + 255) / 256, 256, 0, stream>>>(hs, hsb, n4);
  }

  // 2) qkv = hs @ qkv_w^T in 3 column passes of N=4096 (weight chunk converted per pass)
  for (int p = 0; p < 3; ++p) {
    int n4 = (OD * HID) / 4;    // 4096x2048 chunk
    convert_kernel<<<(n4 + 255) / 256, 256, 0, stream>>>(qkvw + (size_t)p * OD * HID, wchunk, n4);
    gemm_nt_bf16<0><<<dim3(OD / BN, S_LEN / BM), 256, 0, stream>>>(
        hsb, wchunk, qkvb + (size_t)p * OD, HID, QKV_O);
  }

  // 3) RMSNorm + RoPE in place on q,k
  norm_rope_kernel<<<(S_LEN * 2 * NH) / 4, 256, 0, stream>>>(qkvb, pos, qw, kw);

  // 4) causal flash attention -> obuf [s][h*128+d] (bf16; overwrites wchunk region)
  attn_kernel<<<dim3(S_LEN / 128, NH), 256, 0, stream>>>(qkvb, obuf);

  // 5) convert o_proj_w -> bf16 (into ws[0..16M); qkvb dead after attention)
  {
    int n4 = (HID * OD) / 4;
    convert_kernel<<<(n4 + 255) / 256, 256, 0, stream>>>(ow, owb, n4);
  }

  // 6) out = obuf @ o_proj_w^T  (M=2048, N=2048, K=4096), fp32 C into d_out
  gemm_nt_bf16<1><<<dim3(HID / BN, S_LEN / BM), 256, 0, stream>>>(
      obuf, owb, out, OD, HID);
}

// Round 6
// 562.603 us; speedup vs baseline: 1.5545x; 1.2546x over previous
//
#include <hip/hip_runtime.h>
#include <cstdint>
#include <cstddef>

// ---- problem constants ----
static constexpr int S_LEN = 2048;
static constexpr int HID   = 2048;
static constexpr int NH    = 32;
static constexpr int HD    = 128;
static constexpr int OD    = 4096;    // NH*HD
static constexpr int QKV_O = 12288;   // 3*OD

#define AS1 __attribute__((address_space(1)))
#define AS3 __attribute__((address_space(3)))

typedef __attribute__((ext_vector_type(8))) short bf16x8;
typedef __attribute__((ext_vector_type(4))) float f32x4;
typedef __attribute__((ext_vector_type(4))) short s16x4;

__device__ __forceinline__ short f2bf(float f) {
  unsigned u = __float_as_uint(f);
  unsigned r = (u + 0x7fffu + ((u >> 16) & 1u)) >> 16;   // RNE
  return (short)r;
}
__device__ __forceinline__ float bf2f(short s) {
  return __uint_as_float(((unsigned)(unsigned short)s) << 16);
}

// ---------------- fp32 -> bf16 convert (bandwidth-bound) ----------------
__global__ void convert_kernel(const float* __restrict__ in, short* __restrict__ out, int n4) {
  int i = blockIdx.x * blockDim.x + threadIdx.x;
  if (i >= n4) return;
  float4 f = ((const float4*)in)[i];
  s16x4 s;
  s.x = f2bf(f.x); s.y = f2bf(f.y); s.z = f2bf(f.z); s.w = f2bf(f.w);
  ((s16x4*)out)[i] = s;
}

// ---------------- NT bf16 GEMM: C[M,N] = A[M,K] * B[N,K]^T ----------------
// m97 structure: 128x128 tile, BK=32, global_load_lds width16, 16x16x32 MFMA.
// CMODE: 0 = bf16 C, 1 = fp32 C.  ldc = C row stride (elements).
#define BM 128
#define BN 128
#define BK 32

template <int CMODE>
__global__ __launch_bounds__(256, 2) void gemm_nt_bf16(
    const short* __restrict__ A, const short* __restrict__ B, void* __restrict__ Cp,
    int K, int ldc) {
  __shared__ short Alds[BM * BK];   // unpadded: required by global_load_lds lane layout
  __shared__ short Blds[BN * BK];
  const int tid  = threadIdx.x;
  const int lane = tid & 63;
  const int quad = lane >> 4;
  const int col  = lane & 15;
  const int wave = tid >> 6;
  const int m0 = blockIdx.y * BM;
  const int n0 = blockIdx.x * BN;
  const int wm = (wave & 1) * 64;
  const int wn = (wave >> 1) * 64;

  f32x4 acc[4][4] = {};

  for (int k0 = 0; k0 < K; k0 += BK) {
    __syncthreads();
#pragma unroll
    for (int it = 0; it < 2; ++it) {
      int idx = it * 256 + tid;          // 16B chunk index
      int row = idx >> 2;
      int ce  = (idx & 3) * 8;           // element offset within row
      const short* ga = A + (size_t)(m0 + row) * K + k0 + ce;
      const short* gb = B + (size_t)(n0 + row) * K + k0 + ce;
      __builtin_amdgcn_global_load_lds((const AS1 unsigned*)ga, (AS3 unsigned*)&Alds[idx * 8], 16, 0, 0);
      __builtin_amdgcn_global_load_lds((const AS1 unsigned*)gb, (AS3 unsigned*)&Blds[idx * 8], 16, 0, 0);
    }
    __syncthreads();

    bf16x8 a[4], b[4];
#pragma unroll
    for (int i = 0; i < 4; ++i) {
      a[i] = *(const bf16x8*)&Alds[(wm + i * 16 + col) * BK + quad * 8];
      b[i] = *(const bf16x8*)&Blds[(wn + i * 16 + col) * BK + quad * 8];
    }
#pragma unroll
    for (int i = 0; i < 4; ++i)
#pragma unroll
      for (int j = 0; j < 4; ++j)
        acc[i][j] = __builtin_amdgcn_mfma_f32_16x16x32_bf16(a[i], b[j], acc[i][j], 0, 0, 0);
  }

  // epilogue: C/D layout col=lane&15, row=quad*4+reg (verified m89/m91)
#pragma unroll
  for (int i = 0; i < 4; ++i)
#pragma unroll
    for (int j = 0; j < 4; ++j)
#pragma unroll
      for (int r = 0; r < 4; ++r) {
        int rr = m0 + wm + i * 16 + quad * 4 + r;
        int cc = n0 + wn + j * 16 + col;
        if (CMODE == 1)
          ((float*)Cp)[(size_t)rr * ldc + cc] = acc[i][j][r];
        else
          ((short*)Cp)[(size_t)rr * ldc + cc] = f2bf(acc[i][j][r]);
      }
}

// ---------------- per-(s, q/k, head) RMSNorm + RoPE, in place on bf16 qkv ----------------
__global__ void norm_rope_kernel(short* __restrict__ qkv,
                                 const int* __restrict__ positions,
                                 const float* __restrict__ qw,
                                 const float* __restrict__ kw) {
  int item = blockIdx.x * 4 + (threadIdx.x >> 6);  // (s, which, head)
  int lane = threadIdx.x & 63;
  int head  = item & 31;
  int which = (item >> 5) & 1;
  int s     = item >> 6;
  const float* w = which ? kw : qw;
  short* base = qkv + (size_t)s * QKV_O + which * OD + head * HD;

  float x1 = bf2f(base[lane]);
  float x2 = bf2f(base[lane + 64]);
  float ss = x1 * x1 + x2 * x2;
#pragma unroll
  for (int d = 32; d; d >>= 1) ss += __shfl_xor(ss, d);
  float r = rsqrtf(ss * (1.0f / 128.0f) + 1e-5f);
  float xn1 = x1 * r * w[lane];
  float xn2 = x2 * r * w[lane + 64];

  float pos = (float)positions[s];
  float inv_freq = exp2f((float)lane * (-13.287712379549449f / 64.0f));
  float f = pos * inv_freq;
  float c = cosf(f), sn = sinf(f);
  base[lane]      = f2bf(xn1 * c - xn2 * sn);
  base[lane + 64] = f2bf(xn2 * c + xn1 * sn);
}

// ---------------- V pre-transpose: qkv V region -> vtp[h][kt][d][64] tiles ----------------
__global__ void packv_kernel(const short* __restrict__ qkv, short* __restrict__ vtp) {
  __shared__ short T[64][136];   // +8 pad
  const int h  = blockIdx.x;
  const int kt = blockIdx.y;
  const int tid = threadIdx.x;
  {
    int rr = tid >> 2;
    int db = (tid & 3) * 32;
    const short* src = qkv + (size_t)(kt * 64 + rr) * QKV_O + 2 * OD + h * HD + db;
#pragma unroll
    for (int i = 0; i < 4; ++i)
      *(bf16x8*)&T[rr][db + i * 8] = *(const bf16x8*)(src + i * 8);
  }
  __syncthreads();
  {
    int d  = tid >> 1;
    int k0 = (tid & 1) * 32;
    short* dst = vtp + (((size_t)h * 32 + kt) * 128 + d) * 64 + k0;
#pragma unroll
    for (int c = 0; c < 4; ++c) {
      bf16x8 v;
#pragma unroll
      for (int j = 0; j < 8; ++j) v[j] = T[k0 + c * 8 + j][d];
      *(bf16x8*)&dst[c * 8] = v;
    }
  }
}

// ---------------- flash attention (causal), Bq=64/Bk=64, paired q-tiles ----------------
#define L2E 1.4426950408889634f
__global__ __launch_bounds__(256, 2) void attn_kernel(
    const short* __restrict__ qkv, const short* __restrict__ vtp, short* __restrict__ obuf) {
  __shared__ short Klds[64][136];   // K tile [key][d], +8 pad
  __shared__ short Vt[128][72];     // V^T tile [d][key], +8 pad
  __shared__ short Plds[4][16][72]; // per-wave P round-trip, +8 pad

  const int tid  = threadIdx.x;
  const int lane = tid & 63;
  const int wave = tid >> 6;
  const int quad = lane >> 4;
  const int col  = lane & 15;
  const int h    = blockIdx.y;
  const float scale = 0.08838834764831845f;  // 128^-0.5

#pragma unroll 1
  for (int half = 0; half < 2; ++half) {
    const int qt = half == 0 ? blockIdx.x : 31 - blockIdx.x;   // paired: (qt+1)+(32-qt)=33 iters/block
    const int qbase = qt * 64 + wave * 16;

    // Q fragments (A-layout: m=lane&15, k=quad*8+j)
    bf16x8 qf[4];
#pragma unroll
    for (int kf = 0; kf < 4; ++kf)
      qf[kf] = *(const bf16x8*)(qkv + (size_t)(qbase + col) * QKV_O + h * HD + kf * 32 + quad * 8);

    f32x4 o[8] = {};
    float m_i[4], l_i[4];
#pragma unroll
    for (int r = 0; r < 4; ++r) { m_i[r] = -1e30f; l_i[r] = 0.f; }

    for (int kt = 0; kt <= qt; ++kt) {
      __syncthreads();   // prior iter's K/Vt reads complete
      {
        int r  = tid >> 2;
        int cb = (tid & 3) * 32;
        const short* kp = qkv + (size_t)(kt * 64 + r) * QKV_O + OD + h * HD + cb;
#pragma unroll
        for (int i = 0; i < 4; ++i)
          *(bf16x8*)&Klds[r][cb + i * 8] = *(const bf16x8*)(kp + i * 8);
        int vd = tid >> 1;
        int vk = (tid & 1) * 32;
        const short* vp = vtp + (((size_t)h * 32 + kt) * 128 + vd) * 64 + vk;
#pragma unroll
        for (int i = 0; i < 4; ++i)
          *(bf16x8*)&Vt[vd][vk + i * 8] = *(const bf16x8*)(vp + i * 8);
      }
      __syncthreads();

      // S = Q K^T : 4 nf (keys) x 4 kf (d)
      f32x4 sfr[4];
#pragma unroll
      for (int nf = 0; nf < 4; ++nf) {
        f32x4 acc = {};
#pragma unroll
        for (int kf = 0; kf < 4; ++kf) {
          bf16x8 b = *(const bf16x8*)&Klds[nf * 16 + col][kf * 32 + quad * 8];
          acc = __builtin_amdgcn_mfma_f32_16x16x32_bf16(qf[kf], b, acc, 0, 0, 0);
        }
        sfr[nf] = acc;
      }

      // scale (+ causal mask only on the diagonal tile)
      if (kt == qt) {
#pragma unroll
        for (int nf = 0; nf < 4; ++nf)
#pragma unroll
          for (int r = 0; r < 4; ++r) {
            int key = kt * 64 + nf * 16 + col;
            int qg  = qbase + quad * 4 + r;
            float s = sfr[nf][r] * scale;
            sfr[nf][r] = (key > qg) ? -1e30f : s;
          }
      } else {
#pragma unroll
        for (int nf = 0; nf < 4; ++nf)
#pragma unroll
          for (int r = 0; r < 4; ++r) sfr[nf][r] *= scale;
      }

      // online softmax per row r (16-lane group = one quad, col-indexed keys)
#pragma unroll
      for (int r = 0; r < 4; ++r) {
        float mt = fmaxf(fmaxf(sfr[0][r], sfr[1][r]), fmaxf(sfr[2][r], sfr[3][r]));
#pragma unroll
        for (int d = 8; d; d >>= 1) mt = fmaxf(mt, __shfl_xor(mt, d));
        float mnew  = fmaxf(m_i[r], mt);
        float alpha = exp2f((m_i[r] - mnew) * L2E);
        float rs = 0.f;
#pragma unroll
        for (int nf = 0; nf < 4; ++nf) {
          float p = exp2f((sfr[nf][r] - mnew) * L2E);
          sfr[nf][r] = p;
          rs += p;
        }
#pragma unroll
        for (int d = 8; d; d >>= 1) rs += __shfl_xor(rs, d);
        l_i[r] = l_i[r] * alpha + rs;
        m_i[r] = mnew;
#pragma unroll
        for (int nf = 0; nf < 8; ++nf) o[nf][r] *= alpha;
      }

      // P -> LDS (C-layout scatter -> A-layout rows); per-wave buffer, no barrier needed
#pragma unroll
      for (int nf = 0; nf < 4; ++nf)
#pragma unroll
        for (int r = 0; r < 4; ++r)
          Plds[wave][quad * 4 + r][nf * 16 + col] = f2bf(sfr[nf][r]);

      // O += P V : A = P (16x64), B = V^T frags
      bf16x8 pa[2];
#pragma unroll
      for (int kf = 0; kf < 2; ++kf)
        pa[kf] = *(const bf16x8*)&Plds[wave][col][kf * 32 + quad * 8];
#pragma unroll
      for (int nf = 0; nf < 8; ++nf)
#pragma unroll
        for (int kf = 0; kf < 2; ++kf) {
          bf16x8 vb = *(const bf16x8*)&Vt[nf * 16 + col][kf * 32 + quad * 8];
          o[nf] = __builtin_amdgcn_mfma_f32_16x16x32_bf16(pa[kf], vb, o[nf], 0, 0, 0);
        }
    }

    // epilogue: O /= l, write bf16 [s][h*128+d]
#pragma unroll
    for (int r = 0; r < 4; ++r) {
      float inv = 1.0f / l_i[r];
      int sg = qbase + quad * 4 + r;
#pragma unroll
      for (int nf = 0; nf < 8; ++nf)
        obuf[(size_t)sg * OD + h * HD + nf * 16 + col] = f2bf(o[nf][r] * inv);
    }
  }
}

// ---------------- launcher ----------------
extern "C" void kernel_launch(void* const* d_in, const int* in_sizes, int n_in,
                              void* d_out, int out_size, void* d_ws, size_t ws_size,
                              hipStream_t stream) {
  (void)in_sizes; (void)n_in; (void)out_size; (void)ws_size;
  const float* hs   = (const float*)d_in[0];   // [2048][2048] f32
  const int*   pos  = (const int*)d_in[1];     // [2048] int32
  const float* qkvw = (const float*)d_in[2];   // [12288][2048] f32
  const float* qw   = (const float*)d_in[3];   // [128] f32
  const float* kw   = (const float*)d_in[4];   // [128] f32
  const float* ow   = (const float*)d_in[5];   // [2048][4096] f32
  float* out = (float*)d_out;                  // [2048][2048] f32

  // Memory plan (64 MiB ws + d_out scratch, timeline-safe):
  //   ws[ 0..48M): qkvb;  post-attn: owb (bf16 o_proj_w) at ws[0..16M)
  //   ws[48..64M): wchunk during GEMM1; obuf after attention
  //   d_out: hsb (bf16 hidden, 8M) during GEMM1; vtp (16M, packed V^T tiles) after; final out by GEMM2
  char* ws = (char*)d_ws;
  short* qkvb   = (short*)(ws);
  short* wchunk = (short*)(ws + 50331648);
  short* obuf   = (short*)(ws + 50331648);
  short* owb    = (short*)(ws);
  short* hsb    = (short*)d_out;
  short* vtp    = (short*)d_out;

  // 1) convert hidden_states -> bf16 (in d_out scratch)
  {
    int n4 = (S_LEN * HID) / 4;
    convert_kernel<<<(n4 + 255) / 256, 256, 0, stream>>>(hs, hsb, n4);
  }

  // 2) qkv = hs @ qkv_w^T in 3 column passes of N=4096
  for (int p = 0; p < 3; ++p) {
    int n4 = (OD * HID) / 4;
    convert_kernel<<<(n4 + 255) / 256, 256, 0, stream>>>(qkvw + (size_t)p * OD * HID, wchunk, n4);
    gemm_nt_bf16<0><<<dim3(OD / BN, S_LEN / BM), 256, 0, stream>>>(
        hsb, wchunk, qkvb + (size_t)p * OD, HID, QKV_O);
  }

  // 3) RMSNorm + RoPE in place on q,k
  norm_rope_kernel<<<(S_LEN * 2 * NH) / 4, 256, 0, stream>>>(qkvb, pos, qw, kw);

  // 4) pack V^T tiles into d_out (hsb dead after GEMM1)
  packv_kernel<<<dim3(NH, S_LEN / 64), 256, 0, stream>>>(qkvb, vtp);

  // 5) causal flash attention -> obuf [s][h*128+d] (bf16)
  attn_kernel<<<dim3(16, NH), 256, 0, stream>>>(qkvb, vtp, obuf);

  // 6) convert o_proj_w -> bf16 (into ws[0..16M); qkvb dead after attention)
  {
    int n4 = (HID * OD) / 4;
    convert_kernel<<<(n4 + 255) / 256, 256, 0, stream>>>(ow, owb, n4);
  }

  // 7) out = obuf @ o_proj_w^T  (M=2048, N=2048, K=4096), fp32 C into d_out
  gemm_nt_bf16<1><<<dim3(HID / BN, S_LEN / BM), 256, 0, stream>>>(
      obuf, owb, out, OD, HID);
}